// Round 1
// baseline (122.216 us; speedup 1.0000x reference)
//
#include <hip/hip_runtime.h>

// Problem constants (fixed by the reference)
#define N_MOL 2048
#define P_PRO 2048
#define HID   64
#define HEADS 16
#define NGRAPH 64

// Workspace layout (float offsets):
//   a_mol  [2048*16] @ 0
//   ea_mol [2048*16] @ 32768
//   a_pro  [2048*16] @ 65536
//   ea_pro [2048*16] @ 98304
//   y_part [2][2048*16] @ 131072   (two p-tile partials, summed in k3)
#define OFF_EAMOL 32768
#define OFF_APRO  65536
#define OFF_YPART 131072

// ---------------------------------------------------------------------------
// Kernel 1: a_mol = mol @ Wmu[:64] + bmu ; a_pro = pro @ Wmu[64:]
// plus exp() of each. 256 blocks x 256 threads; each block = 16 rows x 16 heads.
// Blocks [0,128) handle mol rows, [128,256) handle pro rows.
// ---------------------------------------------------------------------------
__global__ __launch_bounds__(256) void k1_proj(
    const float* __restrict__ mol, const float* __restrict__ pro,
    const float* __restrict__ Wmu, const float* __restrict__ bmu,
    float* __restrict__ ws)
{
    __shared__ float fs[16 * 64];   // 16 rows of features
    __shared__ float wsh[64 * 16];  // 64x16 weight half
    const int tid = threadIdx.x;
    const int blk = blockIdx.x;
    const bool isMol = blk < (N_MOL / 16);
    const int rowbase = (isMol ? blk : blk - (N_MOL / 16)) * 16;
    const float* feats = isMol ? (mol + rowbase * HID) : (pro + rowbase * HID);
    const float* wsrc  = Wmu + (isMol ? 0 : HID * HEADS);

    // Stage 1024 floats each, float4-coalesced
    ((float4*)fs)[tid]  = ((const float4*)feats)[tid];
    ((float4*)wsh)[tid] = ((const float4*)wsrc)[tid];
    __syncthreads();

    const int h = tid & 15, r = tid >> 4;
    float acc = isMol ? bmu[h] : 0.0f;
#pragma unroll
    for (int k = 0; k < 64; ++k)
        acc += fs[r * 64 + k] * wsh[k * 16 + h];

    float* a_out = ws + (isMol ? 0 : OFF_APRO);
    float* e_out = a_out + 32768;   // ea_* sits 32768 floats after a_*
    const int idx = (rowbase + r) * 16 + h;
    a_out[idx] = acc;
    e_out[idx] = __expf(acc);
}

// ---------------------------------------------------------------------------
// Kernel 2: y_part[pt][n][h] = sum over p-tile of (elu(a_mol+a_pro)+1)
//   = sum_p ( s1 = (a_mol+1)+a_pro;  s1>1 ? s1 : ea_mol*ea_pro )
// Grid: 512 blocks = 256 n-tiles (8 rows) x 2 p-tiles (1024 p's).
// Thread (g = tid>>4, h = tid&15) covers p = pbase + i*16 + g, i in [0,64):
// flat load index = pbase*16 + i*256 + tid  -> fully coalesced 1 KiB/wave-pair.
// ---------------------------------------------------------------------------
__global__ __launch_bounds__(256) void k2_pair(
    const float* __restrict__ ws_in, float* __restrict__ y_part)
{
    const float* a_mol  = ws_in;
    const float* ea_mol = ws_in + OFF_EAMOL;
    const float* a_pro  = ws_in + OFF_APRO;
    const float* ea_pro = ws_in + OFF_APRO + 32768;

    const int tid = threadIdx.x;
    const int h = tid & 15, g = tid >> 4;
    const int nt = blockIdx.x >> 1, pt = blockIdx.x & 1;
    const int nbase = nt * 8;
    const int pflat = pt * (1024 * 16);

    float a1[8], ea[8], acc[8];
#pragma unroll
    for (int j = 0; j < 8; ++j) {
        const int idx = (nbase + j) * 16 + h;
        a1[j]  = a_mol[idx] + 1.0f;   // fold the +1 so compare is s1>1
        ea[j]  = ea_mol[idx];
        acc[j] = 0.0f;
    }

#pragma unroll 4
    for (int i = 0; i < 64; ++i) {
        const int flat = pflat + i * 256 + tid;
        const float bp = a_pro[flat];
        const float eb = ea_pro[flat];
#pragma unroll
        for (int j = 0; j < 8; ++j) {
            const float s1 = a1[j] + bp;
            const float e  = ea[j] * eb;
            acc[j] += (s1 > 1.0f) ? s1 : e;
        }
    }

    // Reduce the 16 p-groups per (row j, head h)
    __shared__ float red[8 * 16 * 16];
#pragma unroll
    for (int j = 0; j < 8; ++j)
        red[j * 256 + g * 16 + h] = acc[j];
    __syncthreads();
    if (tid < 128) {
        const int j = tid >> 4, hh = tid & 15;
        float s = 0.0f;
#pragma unroll
        for (int g2 = 0; g2 < 16; ++g2)
            s += red[j * 256 + g2 * 16 + hh];
        y_part[pt * 32768 + (nbase + j) * 16 + hh] = s;
    }
}

// ---------------------------------------------------------------------------
// Kernel 3: segment-sum (sorted batch ids, run-length accumulate) + MLP head.
// Single block, 256 threads: thread = (chunk of 128 atoms) x (head).
// ---------------------------------------------------------------------------
__global__ __launch_bounds__(256) void k3_final(
    const float* __restrict__ y_part, const int* __restrict__ batch,
    const float* __restrict__ W1, const float* __restrict__ b1,
    const float* __restrict__ W2, const float* __restrict__ b2,
    float* __restrict__ out)
{
    __shared__ float ysum[NGRAPH * HEADS];
    const int tid = threadIdx.x;
    for (int i = tid; i < NGRAPH * HEADS; i += 256) ysum[i] = 0.0f;
    __syncthreads();

    const int h = tid & 15, c = tid >> 4;  // 16 chunks x 128 atoms
    const float* yp0 = y_part;
    const float* yp1 = y_part + 32768;
    float racc = 0.0f;
    int cur = -1;
    for (int i = 0; i < 128; ++i) {
        const int n = c * 128 + i;
        const int b = batch[n];
        if (b != cur) {
            if (cur >= 0) atomicAdd(&ysum[cur * 16 + h], racc);
            cur = b; racc = 0.0f;
        }
        racc += yp0[n * 16 + h] + yp1[n * 16 + h];
    }
    if (cur >= 0) atomicAdd(&ysum[cur * 16 + h], racc);
    __syncthreads();

    if (tid < NGRAPH) {
        const int b = tid;
        float yv[HEADS];
#pragma unroll
        for (int hh = 0; hh < HEADS; ++hh) yv[hh] = ysum[b * 16 + hh] * 0.001f;
        float o = b2[0];
#pragma unroll
        for (int j = 0; j < 32; ++j) {
            float t = b1[j];
#pragma unroll
            for (int hh = 0; hh < HEADS; ++hh) t += yv[hh] * W1[hh * 32 + j];
            t = (t > 0.0f) ? t : (__expf(t) - 1.0f);   // elu
            o += t * W2[j];
        }
        out[b] = o;
    }
}

extern "C" void kernel_launch(void* const* d_in, const int* in_sizes, int n_in,
                              void* d_out, int out_size, void* d_ws, size_t ws_size,
                              hipStream_t stream) {
    const float* mol   = (const float*)d_in[0];
    const float* pro   = (const float*)d_in[1];
    const float* Wmu   = (const float*)d_in[2];
    const float* bmu   = (const float*)d_in[3];
    const float* W1    = (const float*)d_in[4];
    const float* b1    = (const float*)d_in[5];
    const float* W2    = (const float*)d_in[6];
    const float* b2    = (const float*)d_in[7];
    const int*   batch = (const int*)d_in[8];
    float* ws = (float*)d_ws;

    hipLaunchKernelGGL(k1_proj, dim3(256), dim3(256), 0, stream,
                       mol, pro, Wmu, bmu, ws);
    hipLaunchKernelGGL(k2_pair, dim3(512), dim3(256), 0, stream,
                       ws, ws + OFF_YPART);
    hipLaunchKernelGGL(k3_final, dim3(1), dim3(256), 0, stream,
                       ws + OFF_YPART, batch, W1, b1, W2, b2, (float*)d_out);
}

// Round 2
// 103.821 us; speedup vs baseline: 1.1772x; 1.1772x over previous
//
#include <hip/hip_runtime.h>

// Problem constants (fixed by the reference)
#define N_MOL 2048
#define P_PRO 2048
#define HID   64
#define HEADS 16
#define NGRAPH 64

// Workspace layout (float offsets):
//   a_mol  [2048*16] @ 0
//   ea_mol [2048*16] @ 32768
//   a_pro  [2048*16] @ 65536
//   ea_pro [2048*16] @ 98304
//   ysum   [64*16]   @ 131072   (segment-summed y_atom, built by k2 atomics)
#define OFF_EAMOL 32768
#define OFF_APRO  65536
#define OFF_YSUM  131072

// ---------------------------------------------------------------------------
// Kernel 1: a_mol = mol @ Wmu[:64] + bmu ; a_pro = pro @ Wmu[64:]
// plus exp() of each. 256 blocks x 256 threads; each block = 16 rows x 16 heads.
// Block 0 additionally zeroes ysum (ws is re-poisoned 0xAA before every launch).
// ---------------------------------------------------------------------------
__global__ __launch_bounds__(256) void k1_proj(
    const float* __restrict__ mol, const float* __restrict__ pro,
    const float* __restrict__ Wmu, const float* __restrict__ bmu,
    float* __restrict__ ws)
{
    __shared__ float fs[16 * 64];   // 16 rows of features
    __shared__ float wsh[64 * 16];  // 64x16 weight half
    const int tid = threadIdx.x;
    const int blk = blockIdx.x;

    if (blk == 0) {                 // zero ysum[1024]: 256 threads x float4
        float4 z; z.x = z.y = z.z = z.w = 0.0f;
        ((float4*)(ws + OFF_YSUM))[tid] = z;
    }

    const bool isMol = blk < (N_MOL / 16);
    const int rowbase = (isMol ? blk : blk - (N_MOL / 16)) * 16;
    const float* feats = isMol ? (mol + rowbase * HID) : (pro + rowbase * HID);
    const float* wsrc  = Wmu + (isMol ? 0 : HID * HEADS);

    // Stage 1024 floats each, float4-coalesced
    ((float4*)fs)[tid]  = ((const float4*)feats)[tid];
    ((float4*)wsh)[tid] = ((const float4*)wsrc)[tid];
    __syncthreads();

    const int h = tid & 15, r = tid >> 4;
    float acc = isMol ? bmu[h] : 0.0f;
#pragma unroll
    for (int k = 0; k < 64; ++k)
        acc += fs[r * 64 + k] * wsh[k * 16 + h];

    float* a_out = ws + (isMol ? 0 : OFF_APRO);
    float* e_out = a_out + 32768;   // ea_* sits 32768 floats after a_*
    const int idx = (rowbase + r) * 16 + h;
    a_out[idx] = acc;
    e_out[idx] = __expf(acc);
}

// ---------------------------------------------------------------------------
// Kernel 2: y_atom[n][h] = sum_p (elu(a_mol+a_pro)+1)
//   = sum_p ( s1 = (a_mol+1)+a_pro;  s1>1 ? s1 : ea_mol*ea_pro )
// then segment-sum fused: atomicAdd(&ysum[batch[n]*16+h], partial).
// Grid: 1024 blocks = 256 n-tiles (8 rows) x 4 p-tiles (512 p's each).
// Thread covers flat load index = pflat + i*256 + tid -> fully coalesced.
// ---------------------------------------------------------------------------
__global__ __launch_bounds__(256) void k2_pair(
    const float* __restrict__ ws_in, const int* __restrict__ batch,
    float* __restrict__ ysum)
{
    const float* a_mol  = ws_in;
    const float* ea_mol = ws_in + OFF_EAMOL;
    const float* a_pro  = ws_in + OFF_APRO;
    const float* ea_pro = ws_in + OFF_APRO + 32768;

    const int tid = threadIdx.x;
    const int h = tid & 15, g = tid >> 4;
    const int nt = blockIdx.x >> 2, pt = blockIdx.x & 3;
    const int nbase = nt * 8;
    const int pflat = pt * (512 * 16);

    float a1[8], ea[8], acc[8];
#pragma unroll
    for (int j = 0; j < 8; ++j) {
        const int idx = (nbase + j) * 16 + h;
        a1[j]  = a_mol[idx] + 1.0f;   // fold the +1 so compare is s1>1
        ea[j]  = ea_mol[idx];
        acc[j] = 0.0f;
    }

#pragma unroll 4
    for (int i = 0; i < 32; ++i) {
        const int flat = pflat + i * 256 + tid;
        const float bp = a_pro[flat];
        const float eb = ea_pro[flat];
#pragma unroll
        for (int j = 0; j < 8; ++j) {
            const float s1 = a1[j] + bp;
            const float e  = ea[j] * eb;
            acc[j] += (s1 > 1.0f) ? s1 : e;
        }
    }

    // Reduce the 16 p-groups per (row j, head h), then one atomic per (j,h)
    __shared__ float red[8 * 16 * 16];
#pragma unroll
    for (int j = 0; j < 8; ++j)
        red[j * 256 + g * 16 + h] = acc[j];
    __syncthreads();
    if (tid < 128) {
        const int j = tid >> 4, hh = tid & 15;
        float s = 0.0f;
#pragma unroll
        for (int g2 = 0; g2 < 16; ++g2)
            s += red[j * 256 + g2 * 16 + hh];
        const int b = batch[nbase + j];
        atomicAdd(&ysum[b * 16 + hh], s);
    }
}

// ---------------------------------------------------------------------------
// Kernel 3: tiny MLP head only. 1 block, 64 threads (one per graph).
// ---------------------------------------------------------------------------
__global__ __launch_bounds__(64) void k3_final(
    const float* __restrict__ ysum,
    const float* __restrict__ W1, const float* __restrict__ b1,
    const float* __restrict__ W2, const float* __restrict__ b2,
    float* __restrict__ out)
{
    const int b = threadIdx.x;
    float yv[HEADS];
#pragma unroll
    for (int hh = 0; hh < HEADS; ++hh) yv[hh] = ysum[b * 16 + hh] * 0.001f;
    float o = b2[0];
#pragma unroll
    for (int j = 0; j < 32; ++j) {
        float t = b1[j];
#pragma unroll
        for (int hh = 0; hh < HEADS; ++hh) t += yv[hh] * W1[hh * 32 + j];
        t = (t > 0.0f) ? t : (__expf(t) - 1.0f);   // elu
        o += t * W2[j];
    }
    out[b] = o;
}

extern "C" void kernel_launch(void* const* d_in, const int* in_sizes, int n_in,
                              void* d_out, int out_size, void* d_ws, size_t ws_size,
                              hipStream_t stream) {
    const float* mol   = (const float*)d_in[0];
    const float* pro   = (const float*)d_in[1];
    const float* Wmu   = (const float*)d_in[2];
    const float* bmu   = (const float*)d_in[3];
    const float* W1    = (const float*)d_in[4];
    const float* b1    = (const float*)d_in[5];
    const float* W2    = (const float*)d_in[6];
    const float* b2    = (const float*)d_in[7];
    const int*   batch = (const int*)d_in[8];
    float* ws = (float*)d_ws;

    hipLaunchKernelGGL(k1_proj, dim3(256), dim3(256), 0, stream,
                       mol, pro, Wmu, bmu, ws);
    hipLaunchKernelGGL(k2_pair, dim3(1024), dim3(256), 0, stream,
                       ws, batch, ws + OFF_YSUM);
    hipLaunchKernelGGL(k3_final, dim3(1), dim3(64), 0, stream,
                       ws + OFF_YSUM, W1, b1, W2, b2, (float*)d_out);
}

// Round 3
// 86.864 us; speedup vs baseline: 1.4070x; 1.1952x over previous
//
#include <hip/hip_runtime.h>

// Problem constants (fixed by the reference)
#define N_MOL 2048
#define P_PRO 2048
#define HID   64
#define HEADS 16
#define NGRAPH 64

// Workspace layout (float offsets):
//   pe_mol [2048*16][2] @ 0       interleaved {a_mol, exp(a_mol)}
//   pe_pro [2048*16][2] @ 65536   interleaved {a_pro, exp(a_pro)}
//   y_part [4][2048*16] @ 131072  per-p-tile partial row sums
#define OFF_PEPRO 65536
#define OFF_YPART 131072

// ---------------------------------------------------------------------------
// Kernel 1: a_mol = mol @ Wmu[:64] + bmu ; a_pro = pro @ Wmu[64:]
// Stores interleaved {a, exp(a)} float2 so k2 needs one dwordx2 per pair.
// 256 blocks x 256 threads; each block = 16 rows x 16 heads.
// ---------------------------------------------------------------------------
__global__ __launch_bounds__(256) void k1_proj(
    const float* __restrict__ mol, const float* __restrict__ pro,
    const float* __restrict__ Wmu, const float* __restrict__ bmu,
    float* __restrict__ ws)
{
    __shared__ float fs[16 * 64];   // 16 rows of features
    __shared__ float wsh[64 * 16];  // 64x16 weight half
    const int tid = threadIdx.x;
    const int blk = blockIdx.x;
    const bool isMol = blk < (N_MOL / 16);
    const int rowbase = (isMol ? blk : blk - (N_MOL / 16)) * 16;
    const float* feats = isMol ? (mol + rowbase * HID) : (pro + rowbase * HID);
    const float* wsrc  = Wmu + (isMol ? 0 : HID * HEADS);

    // Stage 1024 floats each, float4-coalesced
    ((float4*)fs)[tid]  = ((const float4*)feats)[tid];
    ((float4*)wsh)[tid] = ((const float4*)wsrc)[tid];
    __syncthreads();

    const int h = tid & 15, r = tid >> 4;
    float acc = isMol ? bmu[h] : 0.0f;
#pragma unroll
    for (int k = 0; k < 64; ++k)
        acc += fs[r * 64 + k] * wsh[k * 16 + h];

    float2* pe = (float2*)(ws + (isMol ? 0 : OFF_PEPRO));
    const int idx = (rowbase + r) * 16 + h;
    float2 v; v.x = acc; v.y = __expf(acc);
    pe[idx] = v;            // 8B/lane, consecutive h -> fully coalesced
}

// ---------------------------------------------------------------------------
// Kernel 2: y_part[pt][n][h] = sum over p-tile of (elu(a_mol+a_pro)+1)
//   = sum_p ( s1 = (a_mol+1)+a_pro;  s1>1 ? s1 : ea_mol*ea_pro )
// Grid: 1024 blocks = 256 n-tiles (8 rows) x 4 p-tiles (512 p's each).
// Inner loop: one dwordx2 load per thread per iter (flat = pflat+i*256+tid,
// fully coalesced), 8 rows of register reuse, NO atomics.
// ---------------------------------------------------------------------------
__global__ __launch_bounds__(256) void k2_pair(
    const float* __restrict__ ws_in, float* __restrict__ y_part)
{
    const float2* pe_mol = (const float2*)ws_in;
    const float2* pe_pro = (const float2*)(ws_in + OFF_PEPRO);

    const int tid = threadIdx.x;
    const int h = tid & 15, g = tid >> 4;
    const int nt = blockIdx.x >> 2, pt = blockIdx.x & 3;
    const int nbase = nt * 8;
    const int pflat = pt * (512 * 16);

    float a1[8], ea[8], acc[8];
#pragma unroll
    for (int j = 0; j < 8; ++j) {
        const float2 m = pe_mol[(nbase + j) * 16 + h];
        a1[j]  = m.x + 1.0f;   // fold the +1 so compare is s1>1
        ea[j]  = m.y;
        acc[j] = 0.0f;
    }

#pragma unroll 4
    for (int i = 0; i < 32; ++i) {
        const float2 p = pe_pro[pflat + i * 256 + tid];
        const float bp = p.x, eb = p.y;
#pragma unroll
        for (int j = 0; j < 8; ++j) {
            const float s1 = a1[j] + bp;
            const float e  = ea[j] * eb;
            acc[j] += (s1 > 1.0f) ? s1 : e;
        }
    }

    // Reduce the 16 p-groups per (row j, head h); one store per (j,h)
    __shared__ float red[8 * 16 * 16];
#pragma unroll
    for (int j = 0; j < 8; ++j)
        red[j * 256 + g * 16 + h] = acc[j];
    __syncthreads();
    if (tid < 128) {
        const int j = tid >> 4, hh = tid & 15;
        float s = 0.0f;
#pragma unroll
        for (int g2 = 0; g2 < 16; ++g2)
            s += red[j * 256 + g2 * 16 + hh];
        y_part[pt * 32768 + (nbase + j) * 16 + hh] = s;
    }
}

// ---------------------------------------------------------------------------
// Kernel 3: per-graph segment-sum + fused MLP head.
// 64 blocks (one per graph) x 256 threads. batch is SORTED, so graph b owns
// a contiguous row range [start,end) — found in parallel, summed coalesced.
// ---------------------------------------------------------------------------
__global__ __launch_bounds__(256) void k3_seg_mlp(
    const float* __restrict__ y_part, const int* __restrict__ batch,
    const float* __restrict__ W1, const float* __restrict__ b1,
    const float* __restrict__ W2, const float* __restrict__ b2,
    float* __restrict__ out)
{
    const int tid = threadIdx.x;
    const int b = blockIdx.x;
    __shared__ int s_start, s_end;
    if (tid == 0) { s_start = 0; s_end = 0; }
    __syncthreads();

    // Range-find in the sorted batch array (empty graph -> [0,0))
    for (int i = tid; i < N_MOL; i += 256) {
        const int bi = batch[i];
        if (bi == b) {
            if (i == 0 || batch[i - 1] != b) s_start = i;
            if (i == N_MOL - 1 || batch[i + 1] != b) s_end = i + 1;
        }
    }
    __syncthreads();

    // Coalesced sum of the 4 p-tile partials over the row range
    const int h = tid & 15, rr = tid >> 4;   // 16 row-lanes x 16 heads
    float s = 0.0f;
    for (int n = s_start + rr; n < s_end; n += 16) {
        const int o = n * 16 + h;
        s += y_part[o] + y_part[32768 + o] + y_part[65536 + o] + y_part[98304 + o];
    }

    __shared__ float red[256];
    __shared__ float ysum[HEADS];
    red[tid] = s;
    __syncthreads();
    if (tid < 16) {
        float c = 0.0f;
#pragma unroll
        for (int r2 = 0; r2 < 16; ++r2) c += red[r2 * 16 + tid];
        ysum[tid] = c * 0.001f;
    }
    __syncthreads();

    // MLP: 32 hidden units on lanes 0..31, shuffle-reduce the output dot
    if (tid < 32) {
        const int j = tid;
        float t = b1[j];
#pragma unroll
        for (int hh = 0; hh < HEADS; ++hh) t += ysum[hh] * W1[hh * 32 + j];
        t = (t > 0.0f) ? t : (__expf(t) - 1.0f);   // elu
        float v = t * W2[j];
#pragma unroll
        for (int off = 16; off > 0; off >>= 1) v += __shfl_down(v, off, 32);
        if (tid == 0) out[b] = v + b2[0];
    }
}

extern "C" void kernel_launch(void* const* d_in, const int* in_sizes, int n_in,
                              void* d_out, int out_size, void* d_ws, size_t ws_size,
                              hipStream_t stream) {
    const float* mol   = (const float*)d_in[0];
    const float* pro   = (const float*)d_in[1];
    const float* Wmu   = (const float*)d_in[2];
    const float* bmu   = (const float*)d_in[3];
    const float* W1    = (const float*)d_in[4];
    const float* b1    = (const float*)d_in[5];
    const float* W2    = (const float*)d_in[6];
    const float* b2    = (const float*)d_in[7];
    const int*   batch = (const int*)d_in[8];
    float* ws = (float*)d_ws;

    hipLaunchKernelGGL(k1_proj, dim3(256), dim3(256), 0, stream,
                       mol, pro, Wmu, bmu, ws);
    hipLaunchKernelGGL(k2_pair, dim3(1024), dim3(256), 0, stream,
                       ws, ws + OFF_YPART);
    hipLaunchKernelGGL(k3_seg_mlp, dim3(NGRAPH), dim3(256), 0, stream,
                       ws + OFF_YPART, batch, W1, b1, W2, b2, (float*)d_out);
}